// Round 4
// baseline (107.196 us; speedup 1.0000x reference)
//
#include <hip/hip_runtime.h>
#include <math.h>

// LDE via MFMA, fused single kernel.
// dis^2 = ||x||^2 - 2*(x.dic) + ||dic||^2; GEMM1 (x.dicT) and GEMM2 (e^T.x)
// on mfma_f32_16x16x32_bf16 with bf16 hi/lo split for the cross term.
// R4: dic staged to LDS as bf16 hi/lo once per block (was re-converted in the
// k-loop); combine fused via last-block-per-(b,dg) device-scope atomic.

constexpr int Bn = 8, Tn = 2048, Dn = 64, Fn = 128;
constexpr int Tc = 64, DG = 32;
constexpr int NCH = Tn / Tc;        // 32 chunks per (b,dg)
constexpr int NDG = Dn / DG;        // 2
constexpr int XS = 136;             // xs row stride (halfwords), 272B = 16B-aligned
constexpr int XT = 72;              // xsT row stride
constexpr int ESS = 72;             // es row stride
constexpr int DS = 136;             // dic LDS row stride
constexpr int RECF = DG * Fn + 2 * DG;        // 4160 floats per record
constexpr size_t CNT_OFF = (size_t)12 << 20;  // counters at ws + 12 MB (records end at 8.52 MB)
constexpr int NGRP = Bn * NDG;                // 16 counters

typedef short short8 __attribute__((ext_vector_type(8)));
typedef float f32x4 __attribute__((ext_vector_type(4)));

__device__ inline unsigned short f2bf(float v) {          // RNE float->bf16
    union { float f; unsigned u; } c; c.f = v;
    return (unsigned short)((c.u + 0x7FFF + ((c.u >> 16) & 1)) >> 16);
}
__device__ inline float bf2f(unsigned short h) {
    union { unsigned u; float f; } c; c.u = ((unsigned)h) << 16;
    return c.f;
}

__global__ __launch_bounds__(256) void lde_fused(
    const float* __restrict__ x, const float* __restrict__ dic,
    const float* __restrict__ wei, float* __restrict__ ws,
    unsigned int* __restrict__ cnt, float* __restrict__ out)
{
    const int b  = blockIdx.x & 7;                 // low bits -> XCD affinity for x[b]
    const int dg = (blockIdx.x >> 3) & (NDG - 1);
    const int tc = blockIdx.x >> 4;
    const int t0 = tc * Tc;
    const int d0 = dg * DG;

    __shared__ unsigned short xs_hi[Tc * XS];      // x bf16 hi, [t][f]    17.0 KB
    __shared__ unsigned short xs_lo[Tc * XS];      //                      17.0 KB
    __shared__ unsigned short xsT[Fn * XT];        // x hi, [f][t]         18.0 KB
    __shared__ unsigned short es[DG * ESS];        // e bf16, [d][t]        4.5 KB
    __shared__ unsigned short dic_hi[DG * DS];     // dic bf16 hi, [d][f]   8.5 KB
    __shared__ unsigned short dic_lo[DG * DS];     //                       8.5 KB
    __shared__ float sq[Tc], sp[DG];
    __shared__ float wstat[4][DG], wsum[4][DG];
    __shared__ float sLSE;
    __shared__ int s_last;

    const int tid  = threadIdx.x;
    const int w    = tid >> 6;
    const int lane = tid & 63;
    const int l15  = lane & 15;
    const int quad = lane >> 4;

    // ---- stage x -> bf16 hi/lo; sq[t] = ||x_t||^2 exact ----
    {
        const float4* xb4 = (const float4*)(x + ((size_t)b * Tn + t0) * Fn);
        #pragma unroll
        for (int i = 0; i < 8; ++i) {
            int id4 = i * 256 + tid;               // coalesced float4 index
            int t = id4 >> 5, f4 = id4 & 31;
            float4 v = xb4[id4];
            unsigned short h0 = f2bf(v.x), h1 = f2bf(v.y),
                           h2 = f2bf(v.z), h3 = f2bf(v.w);
            *(ushort4*)&xs_hi[t * XS + f4 * 4] = make_ushort4(h0, h1, h2, h3);
            *(ushort4*)&xs_lo[t * XS + f4 * 4] = make_ushort4(
                f2bf(v.x - bf2f(h0)), f2bf(v.y - bf2f(h1)),
                f2bf(v.z - bf2f(h2)), f2bf(v.w - bf2f(h3)));
            float q = v.x * v.x + v.y * v.y + v.z * v.z + v.w * v.w;
            #pragma unroll
            for (int m = 16; m >= 1; m >>= 1) q += __shfl_xor(q, m);  // 32 lanes share t
            if ((tid & 31) == 0) sq[t] = q;
        }
    }
    // ---- stage dic -> bf16 hi/lo LDS; sp[d] = ||dic_d||^2 exact ----
    {
        int dl = tid >> 3, fq = (tid & 7) * 16;
        const float4* dp = (const float4*)(dic + (size_t)(d0 + dl) * Fn + fq);
        float p = 0.f;
        #pragma unroll
        for (int i = 0; i < 4; ++i) {
            float4 v = dp[i];
            p += v.x * v.x + v.y * v.y + v.z * v.z + v.w * v.w;
            unsigned short h0 = f2bf(v.x), h1 = f2bf(v.y),
                           h2 = f2bf(v.z), h3 = f2bf(v.w);
            *(ushort4*)&dic_hi[dl * DS + fq + i * 4] = make_ushort4(h0, h1, h2, h3);
            *(ushort4*)&dic_lo[dl * DS + fq + i * 4] = make_ushort4(
                f2bf(v.x - bf2f(h0)), f2bf(v.y - bf2f(h1)),
                f2bf(v.z - bf2f(h2)), f2bf(v.w - bf2f(h3)));
        }
        #pragma unroll
        for (int m = 4; m >= 1; m >>= 1) p += __shfl_xor(p, m);
        if ((tid & 7) == 0) sp[dl] = p;
    }
    // ---- logsumexp(wei) (wave 0) ----
    if (tid < 64) {
        float wv = wei[tid];
        float m = wv;
        #pragma unroll
        for (int k = 32; k >= 1; k >>= 1) m = fmaxf(m, __shfl_xor(m, k));
        float e = expf(wv - m), s = e;
        #pragma unroll
        for (int k = 32; k >= 1; k >>= 1) s += __shfl_xor(s, k);
        if (tid == 0) sLSE = m + logf(s);
    }
    __syncthreads();

    // ---- build xsT[f][t] from xs_hi ----
    {
        int f = tid & 127, th = (tid >> 7) * 32;
        #pragma unroll
        for (int g = 0; g < 8; ++g) {
            int tt = th + g * 4;
            *(ushort4*)&xsT[f * XT + tt] = make_ushort4(
                xs_hi[(tt + 0) * XS + f], xs_hi[(tt + 1) * XS + f],
                xs_hi[(tt + 2) * XS + f], xs_hi[(tt + 3) * XS + f]);
        }
    }
    __syncthreads();

    // ---- GEMM1: S[t][d] = x . dicT; wave w owns t-slab w*16 ----
    f32x4 acc1[2] = {{0.f, 0.f, 0.f, 0.f}, {0.f, 0.f, 0.f, 0.f}};
    const int tA = w * 16 + l15;
    #pragma unroll
    for (int k = 0; k < 4; ++k) {
        short8 ahi = *(const short8*)&xs_hi[tA * XS + k * 32 + quad * 8];
        short8 alo = *(const short8*)&xs_lo[tA * XS + k * 32 + quad * 8];
        #pragma unroll
        for (int nt = 0; nt < 2; ++nt) {
            short8 bhi = *(const short8*)&dic_hi[(nt * 16 + l15) * DS + k * 32 + quad * 8];
            short8 blo = *(const short8*)&dic_lo[(nt * 16 + l15) * DS + k * 32 + quad * 8];
            acc1[nt] = __builtin_amdgcn_mfma_f32_16x16x32_bf16(ahi, bhi, acc1[nt], 0, 0, 0);
            acc1[nt] = __builtin_amdgcn_mfma_f32_16x16x32_bf16(alo, bhi, acc1[nt], 0, 0, 0);
            acc1[nt] = __builtin_amdgcn_mfma_f32_16x16x32_bf16(ahi, blo, acc1[nt], 0, 0, 0);
        }
    }

    // ---- logits + chunk softmax stats (D layout: col=l15 -> d, row=quad*4+r -> t) ----
    const float lse = sLSE;
    float logit[2][4], Mc[2], Sc[2], eloc[2][4];
    #pragma unroll
    for (int nt = 0; nt < 2; ++nt) {
        float lsm = wei[d0 + nt * 16 + l15] - lse;
        #pragma unroll
        for (int r = 0; r < 4; ++r) {
            int tt = w * 16 + quad * 4 + r;
            float s2 = sq[tt] - 2.f * acc1[nt][r] + sp[nt * 16 + l15];
            logit[nt][r] = -sqrtf(fmaxf(s2, 0.f)) * lsm;
        }
        float m = fmaxf(fmaxf(logit[nt][0], logit[nt][1]),
                        fmaxf(logit[nt][2], logit[nt][3]));
        m = fmaxf(m, __shfl_xor(m, 16));
        m = fmaxf(m, __shfl_xor(m, 32));
        if (quad == 0) wstat[w][nt * 16 + l15] = m;
    }
    __syncthreads();
    #pragma unroll
    for (int nt = 0; nt < 2; ++nt) {
        int dd = nt * 16 + l15;
        Mc[nt] = fmaxf(fmaxf(wstat[0][dd], wstat[1][dd]),
                       fmaxf(wstat[2][dd], wstat[3][dd]));
        float s = 0.f;
        #pragma unroll
        for (int r = 0; r < 4; ++r) {
            float e = expf(logit[nt][r] - Mc[nt]);
            eloc[nt][r] = e;
            s += e;
        }
        s += __shfl_xor(s, 16);
        s += __shfl_xor(s, 32);
        if (quad == 0) wsum[w][dd] = s;
    }
    __syncthreads();
    float* rec = ws + (size_t)((b * NDG + dg) * NCH + tc) * RECF;
    #pragma unroll
    for (int nt = 0; nt < 2; ++nt) {
        int dd = nt * 16 + l15;
        Sc[nt] = wsum[0][dd] + wsum[1][dd] + wsum[2][dd] + wsum[3][dd];
        #pragma unroll
        for (int r = 0; r < 4; ++r)
            es[dd * ESS + w * 16 + quad * 4 + r] = f2bf(eloc[nt][r]);
    }
    if (w == 0 && quad == 0) {
        rec[DG * Fn + l15]           = Mc[0];
        rec[DG * Fn + 16 + l15]      = Mc[1];
        rec[DG * Fn + DG + l15]      = Sc[0];
        rec[DG * Fn + DG + 16 + l15] = Sc[1];
    }
    __syncthreads();

    // ---- GEMM2: A[d][f] = e^T . x_hi; wave w owns f in [w*32, w*32+32) ----
    f32x4 acc2[2][2] = {{{0.f,0.f,0.f,0.f},{0.f,0.f,0.f,0.f}},
                        {{0.f,0.f,0.f,0.f},{0.f,0.f,0.f,0.f}}};
    const int f0w = w * 32;
    #pragma unroll
    for (int ks = 0; ks < 2; ++ks) {
        short8 af[2];
        #pragma unroll
        for (int mt = 0; mt < 2; ++mt)
            af[mt] = *(const short8*)&es[(mt * 16 + l15) * ESS + ks * 32 + quad * 8];
        #pragma unroll
        for (int nt = 0; nt < 2; ++nt) {
            short8 bfr = *(const short8*)&xsT[(f0w + nt * 16 + l15) * XT + ks * 32 + quad * 8];
            #pragma unroll
            for (int mt = 0; mt < 2; ++mt)
                acc2[mt][nt] = __builtin_amdgcn_mfma_f32_16x16x32_bf16(af[mt], bfr, acc2[mt][nt], 0, 0, 0);
        }
    }
    #pragma unroll
    for (int mt = 0; mt < 2; ++mt)
        #pragma unroll
        for (int nt = 0; nt < 2; ++nt)
            #pragma unroll
            for (int r = 0; r < 4; ++r)
                rec[(mt * 16 + quad * 4 + r) * Fn + f0w + nt * 16 + l15] = acc2[mt][nt][r];

    // ---- last block of (b,dg) group performs the flash-combine ----
    __syncthreads();                               // drain this block's record stores (vmcnt(0))
    if (tid == 0) {
        __threadfence();                           // release: records visible device-wide
        unsigned old = atomicAdd(&cnt[b * NDG + dg], 1u);
        s_last = (old == (unsigned)(NCH - 1));
    }
    __syncthreads();
    if (!s_last) return;
    __threadfence();                               // acquire: see other XCDs' records

    const float* base = ws + (size_t)((b * NDG + dg) * NCH) * RECF;
    const int dl = tid >> 3;                       // 0..31
    const int fq = (tid & 7) * 16;                 // 16 f's per thread
    float M = -INFINITY;
    #pragma unroll 4
    for (int c = 0; c < NCH; ++c)
        M = fmaxf(M, base[(size_t)c * RECF + DG * Fn + dl]);
    float S = 0.f;
    float a[16];
    #pragma unroll
    for (int j = 0; j < 16; ++j) a[j] = 0.f;
    #pragma unroll 2
    for (int c = 0; c < NCH; ++c) {
        const float* rc = base + (size_t)c * RECF;
        float sc = expf(rc[DG * Fn + dl] - M);
        S += rc[DG * Fn + DG + dl] * sc;
        const float4* ap = (const float4*)(rc + dl * Fn + fq);
        #pragma unroll
        for (int i = 0; i < 4; ++i) {
            float4 av = ap[i];
            a[i * 4 + 0] += av.x * sc; a[i * 4 + 1] += av.y * sc;
            a[i * 4 + 2] += av.z * sc; a[i * 4 + 3] += av.w * sc;
        }
    }
    const float inv = 1.0f / S;
    const float4* dp = (const float4*)(dic + (size_t)(d0 + dl) * Fn + fq);
    float4* op = (float4*)(out + ((size_t)b * Dn + d0 + dl) * Fn + fq);
    #pragma unroll
    for (int i = 0; i < 4; ++i) {
        float4 dv = dp[i];
        op[i] = make_float4((a[i * 4 + 0] - S * dv.x) * inv,
                            (a[i * 4 + 1] - S * dv.y) * inv,
                            (a[i * 4 + 2] - S * dv.z) * inv,
                            (a[i * 4 + 3] - S * dv.w) * inv);
    }
}

extern "C" void kernel_launch(void* const* d_in, const int* in_sizes, int n_in,
                              void* d_out, int out_size, void* d_ws, size_t ws_size,
                              hipStream_t stream) {
    const float* x   = (const float*)d_in[0];
    const float* dic = (const float*)d_in[1];
    const float* wei = (const float*)d_in[2];
    float* out = (float*)d_out;
    float* ws  = (float*)d_ws;                       // records: 8.52 MB
    unsigned int* cnt = (unsigned int*)((char*)d_ws + CNT_OFF);

    hipMemsetAsync(cnt, 0, NGRP * sizeof(unsigned int), stream);
    hipLaunchKernelGGL(lde_fused, dim3(Bn * NDG * NCH), dim3(256), 0, stream,
                       x, dic, wei, ws, cnt, out);
}

// Round 6
// 75.213 us; speedup vs baseline: 1.4252x; 1.4252x over previous
//
#include <hip/hip_runtime.h>
#include <math.h>

// LDE via MFMA, two kernels (R6 = R5 with combine-weight bugfix).
// dis^2 = ||x||^2 - 2*(x.dic) + ||dic||^2; GEMM1 (x.dicT, bf16 hi+lo A vs
// bf16 dic) and GEMM2 (e^T.x_hi) on mfma_f32_16x16x32_bf16.
// R6 fix: chunk A-merge weight is exp(Mc-M); Sc multiplies ONLY the S-sum.
// (R5 used Sc*exp(Mc-M) for both -> absmax 1.06.)

constexpr int Bn = 8, Tn = 2048, Dn = 64, Fn = 128;
constexpr int Tc = 64, DG = 32;
constexpr int NCH = Tn / Tc;        // 32 chunks per (b,dg)
constexpr int NDG = Dn / DG;        // 2
constexpr int XT = 72;              // xsT row stride (halfwords); 144B, 16B-aligned
constexpr int ESS = 72;             // es row stride
constexpr int DS = 136;             // dic_hi row stride
constexpr int RECF = DG * Fn + 2 * DG;   // 4160 floats per (b,dg,chunk) record

typedef short short8 __attribute__((ext_vector_type(8)));
typedef float f32x4 __attribute__((ext_vector_type(4)));

__device__ inline unsigned short f2bf(float v) {          // RNE float->bf16
    union { float f; unsigned u; } c; c.f = v;
    return (unsigned short)((c.u + 0x7FFF + ((c.u >> 16) & 1)) >> 16);
}
__device__ inline float bf2f(unsigned short h) {
    union { unsigned u; float f; } c; c.u = ((unsigned)h) << 16;
    return c.f;
}

__global__ __launch_bounds__(256, 4) void lde_main(
    const float* __restrict__ x, const float* __restrict__ dic,
    const float* __restrict__ wei, float* __restrict__ ws)
{
    const int b  = blockIdx.x & 7;                 // low bits -> XCD affinity for x[b]
    const int dg = (blockIdx.x >> 3) & (NDG - 1);
    const int tc = blockIdx.x >> 4;
    const int t0 = tc * Tc;
    const int d0 = dg * DG;

    __shared__ unsigned short xsT[Fn * XT];        // x bf16 hi, [f][t]   18.0 KB
    __shared__ unsigned short es[DG * ESS];        // e bf16, [d][t]       4.5 KB
    __shared__ unsigned short dic_hi[DG * DS];     // dic bf16, [d][f]     8.5 KB
    __shared__ float sq[Tc], sp[DG];
    __shared__ float wstat[4][DG], wsum[4][DG];

    const int tid  = threadIdx.x;
    const int w    = tid >> 6;                     // wave 0..3
    const int lane = tid & 63;
    const int l15  = lane & 15;
    const int quad = lane >> 4;
    const int tA   = w * 16 + l15;                 // this lane's GEMM1 A row (local t)

    // ---- x: strided row loads -> register A-frags (hi+lo); xsT scatter; sq ----
    short8 ahi[4], alo[4];
    {
        const float* xr = x + ((size_t)b * Tn + t0 + tA) * Fn + quad * 8;
        float q = 0.f;
        #pragma unroll
        for (int k = 0; k < 4; ++k) {              // f = k*32 + quad*8 + j
            float4 v0 = *(const float4*)(xr + k * 32);
            float4 v1 = *(const float4*)(xr + k * 32 + 4);
            float vv[8] = {v0.x, v0.y, v0.z, v0.w, v1.x, v1.y, v1.z, v1.w};
            #pragma unroll
            for (int j = 0; j < 8; ++j) {
                unsigned short h = f2bf(vv[j]);
                ahi[k][j] = (short)h;
                alo[k][j] = (short)f2bf(vv[j] - bf2f(h));
                q += vv[j] * vv[j];
                xsT[(k * 32 + quad * 8 + j) * XT + tA] = h;   // transpose scatter
            }
        }
        q += __shfl_xor(q, 16);                    // sum the 4 quads of row tA
        q += __shfl_xor(q, 32);
        if (quad == 0) sq[tA] = q;                 // exact fp32 ||x_t||^2
    }

    // ---- dic -> bf16 LDS (hi only); sp[d] = ||dic_d||^2 exact ----
    {
        int dl = tid >> 3, fq = (tid & 7) * 16;    // 8 threads per d, 16 f each
        const float4* dp = (const float4*)(dic + (size_t)(d0 + dl) * Fn + fq);
        float p = 0.f;
        #pragma unroll
        for (int i = 0; i < 4; ++i) {
            float4 v = dp[i];
            p += v.x * v.x + v.y * v.y + v.z * v.z + v.w * v.w;
            *(ushort4*)&dic_hi[dl * DS + fq + i * 4] =
                make_ushort4(f2bf(v.x), f2bf(v.y), f2bf(v.z), f2bf(v.w));
        }
        #pragma unroll
        for (int m = 4; m >= 1; m >>= 1) p += __shfl_xor(p, m);
        if ((tid & 7) == 0) sp[dl] = p;
    }

    // ---- logsumexp(wei), redundantly per wave ----
    float lse;
    {
        float wv = wei[lane];                      // D=64 = wave width
        float m = wv;
        #pragma unroll
        for (int k = 32; k >= 1; k >>= 1) m = fmaxf(m, __shfl_xor(m, k));
        float e = expf(wv - m), s = e;
        #pragma unroll
        for (int k = 32; k >= 1; k >>= 1) s += __shfl_xor(s, k);
        lse = m + logf(s);
    }
    __syncthreads();                               // xsT, dic_hi, sq, sp ready

    // ---- GEMM1: S[t][d] = x . dicT (A from regs, B from LDS) ----
    f32x4 acc1[2] = {{0.f, 0.f, 0.f, 0.f}, {0.f, 0.f, 0.f, 0.f}};
    #pragma unroll
    for (int k = 0; k < 4; ++k) {
        #pragma unroll
        for (int nt = 0; nt < 2; ++nt) {
            short8 bhi = *(const short8*)&dic_hi[(nt * 16 + l15) * DS + k * 32 + quad * 8];
            acc1[nt] = __builtin_amdgcn_mfma_f32_16x16x32_bf16(ahi[k], bhi, acc1[nt], 0, 0, 0);
            acc1[nt] = __builtin_amdgcn_mfma_f32_16x16x32_bf16(alo[k], bhi, acc1[nt], 0, 0, 0);
        }
    }

    // ---- logits + chunk softmax (C layout: col=l15 -> d, row=quad*4+r -> t) ----
    float logit[2][4], Mc[2], Sc[2], eloc[2][4];
    #pragma unroll
    for (int nt = 0; nt < 2; ++nt) {
        float lsm = wei[d0 + nt * 16 + l15] - lse;
        #pragma unroll
        for (int r = 0; r < 4; ++r) {
            int tt = w * 16 + quad * 4 + r;
            float s2 = sq[tt] - 2.f * acc1[nt][r] + sp[nt * 16 + l15];
            logit[nt][r] = -sqrtf(fmaxf(s2, 0.f)) * lsm;
        }
        float m = fmaxf(fmaxf(logit[nt][0], logit[nt][1]),
                        fmaxf(logit[nt][2], logit[nt][3]));
        m = fmaxf(m, __shfl_xor(m, 16));
        m = fmaxf(m, __shfl_xor(m, 32));
        if (quad == 0) wstat[w][nt * 16 + l15] = m;
    }
    __syncthreads();
    #pragma unroll
    for (int nt = 0; nt < 2; ++nt) {
        int dd = nt * 16 + l15;
        Mc[nt] = fmaxf(fmaxf(wstat[0][dd], wstat[1][dd]),
                       fmaxf(wstat[2][dd], wstat[3][dd]));
        float s = 0.f;
        #pragma unroll
        for (int r = 0; r < 4; ++r) {
            float e = expf(logit[nt][r] - Mc[nt]);
            eloc[nt][r] = e;
            s += e;
        }
        s += __shfl_xor(s, 16);
        s += __shfl_xor(s, 32);
        if (quad == 0) wsum[w][dd] = s;
        #pragma unroll
        for (int r = 0; r < 4; ++r)                // es[d][t] bf16 (GEMM2 A layout)
            es[dd * ESS + w * 16 + quad * 4 + r] = f2bf(eloc[nt][r]);
    }
    __syncthreads();
    float* rec = ws + (size_t)((b * NDG + dg) * NCH + tc) * RECF;
    #pragma unroll
    for (int nt = 0; nt < 2; ++nt) {
        int dd = nt * 16 + l15;
        Sc[nt] = wsum[0][dd] + wsum[1][dd] + wsum[2][dd] + wsum[3][dd];
    }
    if (w == 0 && quad == 0) {                     // chunk stats
        rec[DG * Fn + l15]           = Mc[0];
        rec[DG * Fn + 16 + l15]      = Mc[1];
        rec[DG * Fn + DG + l15]      = Sc[0];
        rec[DG * Fn + DG + 16 + l15] = Sc[1];
    }

    // ---- GEMM2: A[d][f] = e^T . x_hi; wave w owns f in [w*32, w*32+32) ----
    f32x4 acc2[2][2] = {{{0.f,0.f,0.f,0.f},{0.f,0.f,0.f,0.f}},
                        {{0.f,0.f,0.f,0.f},{0.f,0.f,0.f,0.f}}};
    const int f0w = w * 32;
    #pragma unroll
    for (int ks = 0; ks < 2; ++ks) {
        short8 af[2];
        #pragma unroll
        for (int mt = 0; mt < 2; ++mt)
            af[mt] = *(const short8*)&es[(mt * 16 + l15) * ESS + ks * 32 + quad * 8];
        #pragma unroll
        for (int nt = 0; nt < 2; ++nt) {
            short8 bfr = *(const short8*)&xsT[(f0w + nt * 16 + l15) * XT + ks * 32 + quad * 8];
            #pragma unroll
            for (int mt = 0; mt < 2; ++mt)
                acc2[mt][nt] = __builtin_amdgcn_mfma_f32_16x16x32_bf16(af[mt], bfr, acc2[mt][nt], 0, 0, 0);
        }
    }
    #pragma unroll
    for (int mt = 0; mt < 2; ++mt)
        #pragma unroll
        for (int nt = 0; nt < 2; ++nt)
            #pragma unroll
            for (int r = 0; r < 4; ++r)
                rec[(mt * 16 + quad * 4 + r) * Fn + f0w + nt * 16 + l15] = acc2[mt][nt][r];
}

__global__ __launch_bounds__(256) void lde_combine(
    const float* __restrict__ ws, const float* __restrict__ dic,
    float* __restrict__ out)
{
    const int b = blockIdx.x & 7;
    const int d = blockIdx.x >> 3;
    const int dg = d >> 5, dl = d & 31;
    const int tid = threadIdx.x;

    __shared__ float s_sc[NCH];                    // exp(Mc - M) per chunk
    __shared__ float s_S;
    __shared__ float s_pa[Fn];

    const float* base = ws + (size_t)((b * NDG + dg) * NCH) * RECF;

    // ---- M and S across 32 chunks, parallel (lanes 32..63 duplicate) ----
    if (tid < 64) {
        int c = tid & 31;
        float Mc = base[(size_t)c * RECF + DG * Fn + dl];
        float Sc = base[(size_t)c * RECF + DG * Fn + DG + dl];
        float M = Mc;
        #pragma unroll
        for (int m = 32; m >= 1; m >>= 1) M = fmaxf(M, __shfl_xor(M, m));
        float sck = expf(Mc - M);                  // A-merge weight (R6 fix)
        float S = Sc * sck;                        // Sc multiplies ONLY the S-sum
        #pragma unroll
        for (int m = 32; m >= 1; m >>= 1) S += __shfl_xor(S, m);
        if (tid < 32) s_sc[tid] = sck;
        if (tid == 0) s_S = S * 0.5f;              // 64-lane sum counts each chunk twice
    }
    __syncthreads();

    // ---- A-merge: 256 threads = 128 f x 2 chunk-halves, coalesced loads ----
    const int f = tid & 127, h = tid >> 7;
    float a = 0.f;
    #pragma unroll
    for (int i = 0; i < 16; ++i) {
        int c = h * 16 + i;
        a += base[(size_t)c * RECF + dl * Fn + f] * s_sc[c];
    }
    if (h == 1) s_pa[f] = a;
    __syncthreads();
    if (h == 0) {
        a += s_pa[f];
        float S = s_S;
        out[((size_t)b * Dn + d) * Fn + f] = (a - S * dic[d * Fn + f]) / S;
    }
}

extern "C" void kernel_launch(void* const* d_in, const int* in_sizes, int n_in,
                              void* d_out, int out_size, void* d_ws, size_t ws_size,
                              hipStream_t stream) {
    const float* x   = (const float*)d_in[0];
    const float* dic = (const float*)d_in[1];
    const float* wei = (const float*)d_in[2];
    float* out = (float*)d_out;
    float* ws  = (float*)d_ws;                     // records: 8.52 MB

    hipLaunchKernelGGL(lde_main, dim3(Bn * NDG * NCH), dim3(256), 0, stream,
                       x, dic, wei, ws);
    hipLaunchKernelGGL(lde_combine, dim3(Bn * Dn), dim3(256), 0, stream,
                       ws, dic, out);
}